// Round 1
// baseline (537.665 us; speedup 1.0000x reference)
//
#include <hip/hip_runtime.h>
#include <stdint.h>

#define BLOCK 128

struct KeySet {
  uint32_t L0[6], L1[6], R0[6], R1[6];
};

// Threefry-2x32, 20 rounds — shared host/device so the host key-chain
// matches the device bit-for-bit.
__host__ __device__ inline void tf2x32(uint32_t k0, uint32_t k1,
                                       uint32_t x0, uint32_t x1,
                                       uint32_t& o0, uint32_t& o1) {
  const uint32_t k2 = k0 ^ k1 ^ 0x1BD11BDAu;
  x0 += k0; x1 += k1;
#define TFR(r) { x0 += x1; x1 = (x1 << (r)) | (x1 >> (32 - (r))); x1 ^= x0; }
  TFR(13) TFR(15) TFR(26) TFR(6)
  x0 += k1; x1 += k2 + 1u;
  TFR(17) TFR(29) TFR(16) TFR(24)
  x0 += k2; x1 += k0 + 2u;
  TFR(13) TFR(15) TFR(26) TFR(6)
  x0 += k0; x1 += k1 + 3u;
  TFR(17) TFR(29) TFR(16) TFR(24)
  x0 += k1; x1 += k2 + 4u;
  TFR(13) TFR(15) TFR(26) TFR(6)
  x0 += k2; x1 += k0 + 5u;
#undef TFR
  o0 = x0; o1 = x1;
}

// Partitionable-mode random bits: counter = (0, idx), output = o0 ^ o1.
__device__ __forceinline__ uint32_t rbits(uint32_t k0, uint32_t k1, uint32_t idx) {
  uint32_t o0, o1;
  tf2x32(k0, k1, 0u, idx, o0, o1);
  return o0 ^ o1;
}

// JAX gumbel: u = max(tiny, (bitcast((bits>>9)|0x3f800000)-1)*(1-tiny)+tiny);
// (1-tiny) rounds to 1.0f in f32. g = -log(-log(u)). Precise logf on purpose.
__device__ __forceinline__ float gum(uint32_t bits) {
  const float tiny = 1.17549435e-38f;
  float f = __uint_as_float((bits >> 9) | 0x3f800000u) - 1.0f;
  float u = fmaxf(tiny, f + tiny);
  return -logf(-logf(u));
}

__device__ __forceinline__ float expT(float x) {  // Horner, k=12..1: r = 1 + x*r/k
  const float inv[12] = {1.0f/12.0f, 1.0f/11.0f, 0.1f, 1.0f/9.0f, 0.125f, 1.0f/7.0f,
                         1.0f/6.0f, 0.2f, 0.25f, 1.0f/3.0f, 0.5f, 1.0f};
  float r = 1.0f;
#pragma unroll
  for (int i = 0; i < 12; ++i) r = fmaf(x * inv[i], r, 1.0f);
  return r;
}

__device__ __forceinline__ float lnT(float y) {   // k=16..1: r = 1/k - z*r; return z*r
  const float inv[16] = {1.0f/16.0f, 1.0f/15.0f, 1.0f/14.0f, 1.0f/13.0f, 1.0f/12.0f,
                         1.0f/11.0f, 0.1f, 1.0f/9.0f, 0.125f, 1.0f/7.0f, 1.0f/6.0f,
                         0.2f, 0.25f, 1.0f/3.0f, 0.5f, 1.0f};
  float z = y - 1.0f;
  float r = 0.0f;
#pragma unroll
  for (int i = 0; i < 16; ++i) r = fmaf(-z, r, inv[i]);
  return z * r;
}

// softmax over C scores dotted with candidates {1, x0..x3, [prev]}
template<int C>
__device__ __forceinline__ float smdot(const float* s, const float4& xv, float pc) {
  float m = s[0];
#pragma unroll
  for (int c = 1; c < C; ++c) m = fmaxf(m, s[c]);
  float e0 = expf(s[0] - m), e1 = expf(s[1] - m), e2 = expf(s[2] - m),
        e3 = expf(s[3] - m), e4 = expf(s[4] - m);
  float den = e0 + e1 + e2 + e3 + e4;
  float num = fmaf(e4, xv.w, fmaf(e3, xv.z, fmaf(e2, xv.y, fmaf(e1, xv.x, e0))));
  if constexpr (C == 6) {
    float e5 = expf(s[5] - m);
    den += e5;
    num = fmaf(e5, pc, num);
  }
  return num / den;
}

// One tree level. lg = LDS logits [nodes][C][2] for this block's t.
// pv = &pvs[tid]; prev row j at pv[j*BLOCK]. In-place write is hazard-free:
// iteration n reads rows 2n,2n+1 (> n-1, the max row written so far).
template<int C, bool HP>
__device__ __attribute__((noinline)) void level_body(
    int nodes, const float* __restrict__ lg,
    uint32_t kl0, uint32_t kl1, uint32_t kr0, uint32_t kr1,
    uint32_t base, float4 xv, float* __restrict__ pv) {
  for (int n = 0; n < nodes; ++n) {
    float sL[C], sR[C];
#pragma unroll
    for (int c = 0; c < C; ++c) {
      uint32_t idx = base + (uint32_t)(n * C + c);
      sL[c] = lg[(n * C + c) * 2]     + gum(rbits(kl0, kl1, idx));
      sR[c] = lg[(n * C + c) * 2 + 1] + gum(rbits(kr0, kr1, idx));
    }
    float pl = 0.0f, pr = 0.0f;
    if constexpr (HP) {
      pl = pv[(2 * n) * BLOCK];
      pr = pv[(2 * n + 1) * BLOCK];
    }
    float ex = smdot<C>(sL, xv, pl);
    float ey = smdot<C>(sR, xv, pr);
    ex = fminf(fmaxf(ex, -5.0f), 5.0f);   // CLAMP
    ey = fmaxf(ey, 1e-30f);               // LN_EPS
    pv[n * BLOCK] = expT(ex) + lnT(ey);
  }
}

__global__ __launch_bounds__(BLOCK, 4) void eml_kernel(
    const float* __restrict__ x,
    const float* __restrict__ g0, const float* __restrict__ g1,
    const float* __restrict__ g2, const float* __restrict__ g3,
    const float* __restrict__ g4, const float* __restrict__ g5,
    float* __restrict__ out, KeySet ks) {
  __shared__ float lgs[704];            // per-t logits, levels concatenated
  __shared__ float pvs[32 * BLOCK];     // prev rows [node][tid] — conflict-free
  const int tid = threadIdx.x;
  const int t = blockIdx.x & 127;
  const int chunk = blockIdx.x >> 7;    // 0..15

  {
    const float* s0 = g0 + t * 320;     // (T,32,5,2)
    for (int i = tid; i < 320; i += BLOCK) lgs[i] = s0[i];
    const float* s1 = g1 + t * 192;     // (T,16,6,2)
    for (int i = tid; i < 192; i += BLOCK) lgs[320 + i] = s1[i];
    const float* s2 = g2 + t * 96;
    if (tid < 96) lgs[512 + tid] = s2[tid];
    const float* s3 = g3 + t * 48;
    if (tid < 48) lgs[608 + tid] = s3[tid];
    const float* s4 = g4 + t * 24;
    if (tid < 24) lgs[656 + tid] = s4[tid];
    const float* s5 = g5 + t * 12;
    if (tid < 12) lgs[680 + tid] = s5[tid];
  }
  __syncthreads();

  const int b = chunk * BLOCK + tid;                 // 0..2047, coalesced x reads
  const uint32_t bt = (uint32_t)(b * 128 + t);       // flat (b,t) index
  const float4 xv = reinterpret_cast<const float4*>(x)[b];
  float* pv = &pvs[tid];

  level_body<5, false>(32, lgs,       ks.L0[0], ks.L1[0], ks.R0[0], ks.R1[0], bt * 160u, xv, pv);
  level_body<6, true >(16, lgs + 320, ks.L0[1], ks.L1[1], ks.R0[1], ks.R1[1], bt * 96u,  xv, pv);
  level_body<6, true >( 8, lgs + 512, ks.L0[2], ks.L1[2], ks.R0[2], ks.R1[2], bt * 48u,  xv, pv);
  level_body<6, true >( 4, lgs + 608, ks.L0[3], ks.L1[3], ks.R0[3], ks.R1[3], bt * 24u,  xv, pv);
  level_body<6, true >( 2, lgs + 656, ks.L0[4], ks.L1[4], ks.R0[4], ks.R1[4], bt * 12u,  xv, pv);
  level_body<6, true >( 1, lgs + 680, ks.L0[5], ks.L1[5], ks.R0[5], ks.R1[5], bt * 6u,   xv, pv);

  out[bt] = pvs[tid];
}

extern "C" void kernel_launch(void* const* d_in, const int* in_sizes, int n_in,
                              void* d_out, int out_size, void* d_ws, size_t ws_size,
                              hipStream_t stream) {
  const float* x  = (const float*)d_in[0];
  const float* g0 = (const float*)d_in[1];
  const float* g1 = (const float*)d_in[2];
  const float* g2 = (const float*)d_in[3];
  const float* g3 = (const float*)d_in[4];
  const float* g4 = (const float*)d_in[5];
  const float* g5 = (const float*)d_in[6];
  float* out = (float*)d_out;

  // Key chain: key = key(42) = (0,42); per level split(key,3) fold-like:
  // key' = tf(key,(0,0)), kL = tf(key,(0,1)), kR = tf(key,(0,2)).
  KeySet ks;
  uint32_t K0 = 0u, K1 = 42u;
  for (int l = 0; l < 6; ++l) {
    uint32_t n0, n1, a0, a1, c0, c1;
    tf2x32(K0, K1, 0u, 0u, n0, n1);
    tf2x32(K0, K1, 0u, 1u, a0, a1);
    tf2x32(K0, K1, 0u, 2u, c0, c1);
    ks.L0[l] = a0; ks.L1[l] = a1;
    ks.R0[l] = c0; ks.R1[l] = c1;
    K0 = n0; K1 = n1;
  }

  eml_kernel<<<dim3(2048), dim3(BLOCK), 0, stream>>>(x, g0, g1, g2, g3, g4, g5, out, ks);
}

// Round 2
// 375.436 us; speedup vs baseline: 1.4321x; 1.4321x over previous
//
#include <hip/hip_runtime.h>
#include <stdint.h>

#define BLOCK 128

struct KeySet {
  uint32_t L0[6], L1[6], R0[6], R1[6];
};

// Threefry-2x32, 20 rounds — shared host/device so the host key-chain
// matches the device bit-for-bit.
__host__ __device__ inline void tf2x32(uint32_t k0, uint32_t k1,
                                       uint32_t x0, uint32_t x1,
                                       uint32_t& o0, uint32_t& o1) {
  const uint32_t k2 = k0 ^ k1 ^ 0x1BD11BDAu;
  x0 += k0; x1 += k1;
#define TFR(r) { x0 += x1; x1 = (x1 << (r)) | (x1 >> (32 - (r))); x1 ^= x0; }
  TFR(13) TFR(15) TFR(26) TFR(6)
  x0 += k1; x1 += k2 + 1u;
  TFR(17) TFR(29) TFR(16) TFR(24)
  x0 += k2; x1 += k0 + 2u;
  TFR(13) TFR(15) TFR(26) TFR(6)
  x0 += k0; x1 += k1 + 3u;
  TFR(17) TFR(29) TFR(16) TFR(24)
  x0 += k1; x1 += k2 + 4u;
  TFR(13) TFR(15) TFR(26) TFR(6)
  x0 += k2; x1 += k0 + 5u;
#undef TFR
  o0 = x0; o1 = x1;
}

// Partitionable-mode random bits: counter = (0, idx), output = o0 ^ o1.
__device__ __forceinline__ uint32_t rbits(uint32_t k0, uint32_t k1, uint32_t idx) {
  uint32_t o0, o1;
  tf2x32(k0, k1, 0u, idx, o0, o1);
  return o0 ^ o1;
}

// Native hardware transcendentals (v_log_f32 = log2, v_exp_f32 = exp2).
__device__ __forceinline__ float log2_n(float x) { return __builtin_amdgcn_logf(x); }
__device__ __forceinline__ float exp2_n(float x) { return __builtin_amdgcn_exp2f(x); }

// Returns log2(-log2(u)) = -(gumbel * log2e + log2(ln2)).
// Staged logits are pre-transformed lgs' = logit*log2e - log2(ln2), so the
// log2-domain softmax score is  s = lgs' - negg(bits).
__device__ __forceinline__ float negg(uint32_t bits) {
  const float tiny = 1.17549435e-38f;
  float f = __uint_as_float((bits >> 9) | 0x3f800000u) - 1.0f;
  float u = fmaxf(f, tiny);                    // JAX uniform(tiny, 1)
  return log2_n(-log2_n(u));                   // neg folds as input modifier
}

__device__ __forceinline__ float expT(float x) {  // sum_{k=0..12} x^k/k!, Horner
  float r = 2.0876756987868099e-9f;               // 1/12!
  r = fmaf(r, x, 2.5052108385441719e-8f);
  r = fmaf(r, x, 2.7557319223985893e-7f);
  r = fmaf(r, x, 2.7557319223985888e-6f);
  r = fmaf(r, x, 2.4801587301587302e-5f);
  r = fmaf(r, x, 1.9841269841269841e-4f);
  r = fmaf(r, x, 1.3888888888888889e-3f);
  r = fmaf(r, x, 8.3333333333333332e-3f);
  r = fmaf(r, x, 4.1666666666666664e-2f);
  r = fmaf(r, x, 1.6666666666666666e-1f);
  r = fmaf(r, x, 0.5f);
  r = fmaf(r, x, 1.0f);
  r = fmaf(r, x, 1.0f);
  return r;
}

__device__ __forceinline__ float lnT(float y) {   // k=16..1: r = 1/k - z*r; z*r
  const float inv[16] = {1.0f/16.0f, 1.0f/15.0f, 1.0f/14.0f, 1.0f/13.0f, 1.0f/12.0f,
                         1.0f/11.0f, 0.1f, 1.0f/9.0f, 0.125f, 1.0f/7.0f, 1.0f/6.0f,
                         0.2f, 0.25f, 1.0f/3.0f, 0.5f, 1.0f};
  float z = y - 1.0f;
  float r = 0.0f;
#pragma unroll
  for (int i = 0; i < 16; ++i) r = fmaf(-z, r, inv[i]);
  return z * r;
}

// Softmax (log2-domain scores) dotted with candidates {1, x0..x3, [prev]}.
// Max-subtraction kept: without it, 2^(gumbel extreme) * prev(~1e33) can INF.
template<int C>
__device__ __forceinline__ float smdot(const float* s, const float4& xv, float pc) {
  float m = s[0];
#pragma unroll
  for (int c = 1; c < C; ++c) m = fmaxf(m, s[c]);
  float e0 = exp2_n(s[0] - m), e1 = exp2_n(s[1] - m), e2 = exp2_n(s[2] - m),
        e3 = exp2_n(s[3] - m), e4 = exp2_n(s[4] - m);
  float den = e0 + e1 + e2 + e3 + e4;
  float num = fmaf(e4, xv.w, fmaf(e3, xv.z, fmaf(e2, xv.y, fmaf(e1, xv.x, e0))));
  if constexpr (C == 6) {
    float e5 = exp2_n(s[5] - m);
    den += e5;
    num = fmaf(e5, pc, num);
  }
  return num * __builtin_amdgcn_rcpf(den);  // den in [1,6]; ~1ulp is plenty
}

// One tree level. lg = LDS logits (pre-scaled) [nodes][C][2] for this t.
// pv = &pvs[tid]; prev row j at pv[j*BLOCK]. In-place write is hazard-free:
// iteration n reads rows 2n,2n+1 (> n-1, the max row written so far).
template<int C, bool HP>
__device__ __attribute__((noinline)) void level_body(
    int nodes, const float* __restrict__ lg,
    uint32_t kl0, uint32_t kl1, uint32_t kr0, uint32_t kr1,
    uint32_t base, float4 xv, float* __restrict__ pv) {
  for (int n = 0; n < nodes; ++n) {
    float sL[C], sR[C];
#pragma unroll
    for (int c = 0; c < C; ++c) {
      uint32_t idx = base + (uint32_t)(n * C + c);
      sL[c] = lg[(n * C + c) * 2]     - negg(rbits(kl0, kl1, idx));
      sR[c] = lg[(n * C + c) * 2 + 1] - negg(rbits(kr0, kr1, idx));
    }
    float pl = 0.0f, pr = 0.0f;
    if constexpr (HP) {
      pl = pv[(2 * n) * BLOCK];
      pr = pv[(2 * n + 1) * BLOCK];
    }
    float ex = smdot<C>(sL, xv, pl);
    float ey = smdot<C>(sR, xv, pr);
    ex = __builtin_amdgcn_fmed3f(ex, -5.0f, 5.0f);  // CLAMP
    ey = fmaxf(ey, 1e-30f);                          // LN_EPS
    pv[n * BLOCK] = expT(ex) + lnT(ey);
  }
}

__global__ __launch_bounds__(BLOCK, 4) void eml_kernel(
    const float* __restrict__ x,
    const float* __restrict__ g0, const float* __restrict__ g1,
    const float* __restrict__ g2, const float* __restrict__ g3,
    const float* __restrict__ g4, const float* __restrict__ g5,
    float* __restrict__ out, KeySet ks) {
  __shared__ float lgs[704];            // per-t logits (log2-pre-scaled)
  __shared__ float pvs[32 * BLOCK];     // prev rows [node][tid] — conflict-free
  const int tid = threadIdx.x;
  const int t = blockIdx.x & 127;
  const int chunk = blockIdx.x >> 7;    // 0..15

  // lgs' = logit * log2(e) - log2(ln 2): folds the whole gumbel/softmax
  // domain change into staging (log2(ln2) = -0.5287663729448977).
  const float LOG2E = 1.4426950408889634f;
  const float CADD  = 0.5287663729448977f;
  {
    const float* s0 = g0 + t * 320;     // (T,32,5,2)
    for (int i = tid; i < 320; i += BLOCK) lgs[i] = fmaf(s0[i], LOG2E, CADD);
    const float* s1 = g1 + t * 192;     // (T,16,6,2)
    for (int i = tid; i < 192; i += BLOCK) lgs[320 + i] = fmaf(s1[i], LOG2E, CADD);
    const float* s2 = g2 + t * 96;
    if (tid < 96) lgs[512 + tid] = fmaf(s2[tid], LOG2E, CADD);
    const float* s3 = g3 + t * 48;
    if (tid < 48) lgs[608 + tid] = fmaf(s3[tid], LOG2E, CADD);
    const float* s4 = g4 + t * 24;
    if (tid < 24) lgs[656 + tid] = fmaf(s4[tid], LOG2E, CADD);
    const float* s5 = g5 + t * 12;
    if (tid < 12) lgs[680 + tid] = fmaf(s5[tid], LOG2E, CADD);
  }
  __syncthreads();

  const int b = chunk * BLOCK + tid;                 // coalesced x reads
  const uint32_t bt = (uint32_t)(b * 128 + t);       // flat (b,t) index
  const float4 xv = reinterpret_cast<const float4*>(x)[b];
  float* pv = &pvs[tid];

  level_body<5, false>(32, lgs,       ks.L0[0], ks.L1[0], ks.R0[0], ks.R1[0], bt * 160u, xv, pv);
  level_body<6, true >(16, lgs + 320, ks.L0[1], ks.L1[1], ks.R0[1], ks.R1[1], bt * 96u,  xv, pv);
  level_body<6, true >( 8, lgs + 512, ks.L0[2], ks.L1[2], ks.R0[2], ks.R1[2], bt * 48u,  xv, pv);
  level_body<6, true >( 4, lgs + 608, ks.L0[3], ks.L1[3], ks.R0[3], ks.R1[3], bt * 24u,  xv, pv);
  level_body<6, true >( 2, lgs + 656, ks.L0[4], ks.L1[4], ks.R0[4], ks.R1[4], bt * 12u,  xv, pv);
  level_body<6, true >( 1, lgs + 680, ks.L0[5], ks.L1[5], ks.R0[5], ks.R1[5], bt * 6u,   xv, pv);

  out[bt] = pvs[tid];
}

extern "C" void kernel_launch(void* const* d_in, const int* in_sizes, int n_in,
                              void* d_out, int out_size, void* d_ws, size_t ws_size,
                              hipStream_t stream) {
  const float* x  = (const float*)d_in[0];
  const float* g0 = (const float*)d_in[1];
  const float* g1 = (const float*)d_in[2];
  const float* g2 = (const float*)d_in[3];
  const float* g3 = (const float*)d_in[4];
  const float* g4 = (const float*)d_in[5];
  const float* g5 = (const float*)d_in[6];
  float* out = (float*)d_out;

  // Key chain: key = key(42) = (0,42); per level split(key,3) fold-like:
  // key' = tf(key,(0,0)), kL = tf(key,(0,1)), kR = tf(key,(0,2)).
  KeySet ks;
  uint32_t K0 = 0u, K1 = 42u;
  for (int l = 0; l < 6; ++l) {
    uint32_t n0, n1, a0, a1, c0, c1;
    tf2x32(K0, K1, 0u, 0u, n0, n1);
    tf2x32(K0, K1, 0u, 1u, a0, a1);
    tf2x32(K0, K1, 0u, 2u, c0, c1);
    ks.L0[l] = a0; ks.L1[l] = a1;
    ks.R0[l] = c0; ks.R1[l] = c1;
    K0 = n0; K1 = n1;
  }

  eml_kernel<<<dim3(2048), dim3(BLOCK), 0, stream>>>(x, g0, g1, g2, g3, g4, g5, out, ks);
}

// Round 3
// 350.310 us; speedup vs baseline: 1.5348x; 1.0717x over previous
//
#include <hip/hip_runtime.h>
#include <stdint.h>

#define BLOCK 128

struct KeySet {
  uint32_t k0L[6], k1L[6], k2L[6], k0R[6], k1R[6], k2R[6];
};

// Threefry-2x32 host copy for the key chain (split) — bit-exact with device.
__host__ inline void tf2x32(uint32_t k0, uint32_t k1, uint32_t x0, uint32_t x1,
                            uint32_t& o0, uint32_t& o1) {
  const uint32_t k2 = k0 ^ k1 ^ 0x1BD11BDAu;
  x0 += k0; x1 += k1;
#define TFR(r) { x0 += x1; x1 = (x1 << (r)) | (x1 >> (32 - (r))); x1 ^= x0; }
  TFR(13) TFR(15) TFR(26) TFR(6)
  x0 += k1; x1 += k2 + 1u;
  TFR(17) TFR(29) TFR(16) TFR(24)
  x0 += k2; x1 += k0 + 2u;
  TFR(13) TFR(15) TFR(26) TFR(6)
  x0 += k0; x1 += k1 + 3u;
  TFR(17) TFR(29) TFR(16) TFR(24)
  x0 += k1; x1 += k2 + 4u;
  TFR(13) TFR(15) TFR(26) TFR(6)
  x0 += k2; x1 += k0 + 5u;
#undef TFR
  o0 = x0; o1 = x1;
}

// Device: counter=(0, idx), x1 arrives with k1 pre-added (x1 = idx + k1).
// Returns o0 ^ o1 (partitionable random_bits). Rotates forced to v_alignbit.
__device__ __forceinline__ uint32_t tf_fold(uint32_t k0, uint32_t k1, uint32_t k2,
                                            uint32_t x1) {
  uint32_t x0 = k0;  // 0 + k0
#define R4(a,b,c,d) \
  x0 += x1; x1 = __builtin_rotateleft32(x1,(a)); x1 ^= x0; \
  x0 += x1; x1 = __builtin_rotateleft32(x1,(b)); x1 ^= x0; \
  x0 += x1; x1 = __builtin_rotateleft32(x1,(c)); x1 ^= x0; \
  x0 += x1; x1 = __builtin_rotateleft32(x1,(d)); x1 ^= x0;
  R4(13,15,26,6)
  x0 += k1; x1 += k2 + 1u;
  R4(17,29,16,24)
  x0 += k2; x1 += k0 + 2u;
  R4(13,15,26,6)
  x0 += k0; x1 += k1 + 3u;
  R4(17,29,16,24)
  x0 += k1; x1 += k2 + 4u;
  R4(13,15,26,6)
#undef R4
  return (x0 + k2) ^ (x1 + (k0 + 5u));
}

// Gumbel-softmax weight factor: e^g = 1/(-ln u) ∝ 1/(-log2 u)  (ln2 cancels
// in num/den). Weights are w'_c = exp(logit_c)*2^-24 from LDS.
__device__ __forceinline__ float wgt(uint32_t bits) {
  const float tiny = 1.17549435e-38f;
  float f = __uint_as_float((bits >> 9) | 0x3f800000u) - 1.0f;
  float u = fmaxf(f, tiny);                 // JAX uniform in [tiny, 1)
  float v = __builtin_amdgcn_logf(u);       // log2(u) ∈ [-126, -1.7e-7]
  return __builtin_amdgcn_rcpf(-v);         // neg folds as input modifier
}

__device__ __forceinline__ float expT(float x) {  // sum_{k=0..12} x^k/k!
  float r = 2.0876756987868099e-9f;               // 1/12!
  r = fmaf(r, x, 2.5052108385441719e-8f);
  r = fmaf(r, x, 2.7557319223985893e-7f);
  r = fmaf(r, x, 2.7557319223985888e-6f);
  r = fmaf(r, x, 2.4801587301587302e-5f);
  r = fmaf(r, x, 1.9841269841269841e-4f);
  r = fmaf(r, x, 1.3888888888888889e-3f);
  r = fmaf(r, x, 8.3333333333333332e-3f);
  r = fmaf(r, x, 4.1666666666666664e-2f);
  r = fmaf(r, x, 1.6666666666666666e-1f);
  r = fmaf(r, x, 0.5f);
  r = fmaf(r, x, 1.0f);
  r = fmaf(r, x, 1.0f);
  return r;
}

__device__ __forceinline__ float lnT(float y) {   // k=16..1: r = 1/k - z*r; z*r
  const float inv[16] = {1.0f/16.0f, 1.0f/15.0f, 1.0f/14.0f, 1.0f/13.0f, 1.0f/12.0f,
                         1.0f/11.0f, 0.1f, 1.0f/9.0f, 0.125f, 1.0f/7.0f, 1.0f/6.0f,
                         0.2f, 0.25f, 1.0f/3.0f, 0.5f, 1.0f};
  float z = y - 1.0f;
  float r = 0.0f;
#pragma unroll
  for (int i = 0; i < 16; ++i) r = fmaf(-z, r, inv[i]);
  return z * r;
}

// One softmax-dot side. w8 = per-node padded weights (8 floats, LDS,
// block-uniform → broadcast reads). x1b = bt*stride + k1 + n*C.
template<int C>
__device__ __forceinline__ float side_eval(const float* __restrict__ w8,
    uint32_t k0, uint32_t k1, uint32_t k2, uint32_t x1b, float4 xv, float pc) {
  float4 wa = *reinterpret_cast<const float4*>(w8);
  float e  = wa.x * wgt(tf_fold(k0, k1, k2, x1b));       // cand = 1
  float den = e, num = e;
  e = wa.y * wgt(tf_fold(k0, k1, k2, x1b + 1u)); den += e; num = fmaf(e, xv.x, num);
  e = wa.z * wgt(tf_fold(k0, k1, k2, x1b + 2u)); den += e; num = fmaf(e, xv.y, num);
  e = wa.w * wgt(tf_fold(k0, k1, k2, x1b + 3u)); den += e; num = fmaf(e, xv.z, num);
  e = w8[4] * wgt(tf_fold(k0, k1, k2, x1b + 4u)); den += e; num = fmaf(e, xv.w, num);
  if constexpr (C == 6) {
    e = w8[5] * wgt(tf_fold(k0, k1, k2, x1b + 5u)); den += e; num = fmaf(e, pc, num);
  }
  return num * __builtin_amdgcn_rcpf(den);
}

// One tree level. wl = LDS weights [node][side][8] for this block's t.
// pv = &pvs[tid]; prev row j at pv[j*BLOCK]. In-place write is hazard-free:
// iteration n reads rows 2n,2n+1 before writing row n (n <= 2n).
template<int C, bool HP>
__device__ __forceinline__ void level_run(int nodes, const float* __restrict__ wl,
    uint32_t k0L, uint32_t k1L, uint32_t k2L,
    uint32_t k0R, uint32_t k1R, uint32_t k2R,
    uint32_t bt, uint32_t stride, float4 xv, float* __restrict__ pv) {
  const uint32_t xbL = bt * stride + k1L;
  const uint32_t xbR = bt * stride + k1R;
  for (int n = 0; n < nodes; ++n) {
    float pl = 0.0f, pr = 0.0f;
    if constexpr (HP) {
      pl = pv[(2 * n) * BLOCK];
      pr = pv[(2 * n + 1) * BLOCK];
    }
    float ex = side_eval<C>(wl + n * 16,     k0L, k1L, k2L, xbL + (uint32_t)(n * C), xv, pl);
    float ey = side_eval<C>(wl + n * 16 + 8, k0R, k1R, k2R, xbR + (uint32_t)(n * C), xv, pr);
    ex = __builtin_amdgcn_fmed3f(ex, -5.0f, 5.0f);  // CLAMP
    ey = fmaxf(ey, 1e-30f);                          // LN_EPS
    pv[n * BLOCK] = expT(ex) + lnT(ey);
  }
}

// Stage one level's logits into padded weight layout [node][side][8]:
// w' = exp2(logit*log2e - 24)  (= e^logit * 2^-24; 2^-24 prevents overflow
// of num against f32 max when rcp weights (<=5.8e6) meet prev ~ 1e33).
template<int C>
__device__ __forceinline__ void stage(const float* __restrict__ g, float* __restrict__ ws,
                                      int t, int N, int woff, int tid) {
  const int total = N * C * 2;
  const float* src = g + t * total;
  for (int i = tid; i < total; i += BLOCK) {
    int n = i / (2 * C);
    int rem = i - n * 2 * C;
    int c = rem >> 1, s = rem & 1;
    ws[woff + n * 16 + s * 8 + c] =
        __builtin_amdgcn_exp2f(fmaf(src[i], 1.4426950408889634f, -24.0f));
  }
}

__global__ __launch_bounds__(BLOCK, 4) void eml_kernel(
    const float* __restrict__ x,
    const float* __restrict__ g0, const float* __restrict__ g1,
    const float* __restrict__ g2, const float* __restrict__ g3,
    const float* __restrict__ g4, const float* __restrict__ g5,
    float* __restrict__ out, KeySet ks) {
  __shared__ float wz[1008];            // padded weights, levels concatenated
  __shared__ float pvs[32 * BLOCK];     // prev rows [node][tid] — conflict-free
  const int tid = threadIdx.x;
  const int t = blockIdx.x & 127;
  const int chunk = blockIdx.x >> 7;    // 0..15

  stage<5>(g0, wz, t, 32,   0, tid);
  stage<6>(g1, wz, t, 16, 512, tid);
  stage<6>(g2, wz, t,  8, 768, tid);
  stage<6>(g3, wz, t,  4, 896, tid);
  stage<6>(g4, wz, t,  2, 960, tid);
  stage<6>(g5, wz, t,  1, 992, tid);
  __syncthreads();

  const int b = chunk * BLOCK + tid;                 // coalesced x reads
  const uint32_t bt = (uint32_t)(b * 128 + t);       // flat (b,t) index
  const float4 xv = reinterpret_cast<const float4*>(x)[b];
  float* pv = &pvs[tid];

  level_run<5, false>(32, wz,       ks.k0L[0], ks.k1L[0], ks.k2L[0],
                      ks.k0R[0], ks.k1R[0], ks.k2R[0], bt, 160u, xv, pv);
  level_run<6, true >(16, wz + 512, ks.k0L[1], ks.k1L[1], ks.k2L[1],
                      ks.k0R[1], ks.k1R[1], ks.k2R[1], bt,  96u, xv, pv);
  level_run<6, true >( 8, wz + 768, ks.k0L[2], ks.k1L[2], ks.k2L[2],
                      ks.k0R[2], ks.k1R[2], ks.k2R[2], bt,  48u, xv, pv);
  level_run<6, true >( 4, wz + 896, ks.k0L[3], ks.k1L[3], ks.k2L[3],
                      ks.k0R[3], ks.k1R[3], ks.k2R[3], bt,  24u, xv, pv);
  level_run<6, true >( 2, wz + 960, ks.k0L[4], ks.k1L[4], ks.k2L[4],
                      ks.k0R[4], ks.k1R[4], ks.k2R[4], bt,  12u, xv, pv);
  level_run<6, true >( 1, wz + 992, ks.k0L[5], ks.k1L[5], ks.k2L[5],
                      ks.k0R[5], ks.k1R[5], ks.k2R[5], bt,   6u, xv, pv);

  out[bt] = pvs[tid];
}

extern "C" void kernel_launch(void* const* d_in, const int* in_sizes, int n_in,
                              void* d_out, int out_size, void* d_ws, size_t ws_size,
                              hipStream_t stream) {
  const float* x  = (const float*)d_in[0];
  const float* g0 = (const float*)d_in[1];
  const float* g1 = (const float*)d_in[2];
  const float* g2 = (const float*)d_in[3];
  const float* g3 = (const float*)d_in[4];
  const float* g4 = (const float*)d_in[5];
  const float* g5 = (const float*)d_in[6];
  float* out = (float*)d_out;

  // Key chain: key(42) = (0,42); per level split(key,3) fold-like:
  // key' = tf(key,(0,0)), kL = tf(key,(0,1)), kR = tf(key,(0,2)).
  KeySet ks;
  uint32_t K0 = 0u, K1 = 42u;
  for (int l = 0; l < 6; ++l) {
    uint32_t n0, n1, a0, a1, c0, c1;
    tf2x32(K0, K1, 0u, 0u, n0, n1);
    tf2x32(K0, K1, 0u, 1u, a0, a1);
    tf2x32(K0, K1, 0u, 2u, c0, c1);
    ks.k0L[l] = a0; ks.k1L[l] = a1; ks.k2L[l] = a0 ^ a1 ^ 0x1BD11BDAu;
    ks.k0R[l] = c0; ks.k1R[l] = c1; ks.k2R[l] = c0 ^ c1 ^ 0x1BD11BDAu;
    K0 = n0; K1 = n1;
  }

  eml_kernel<<<dim3(2048), dim3(BLOCK), 0, stream>>>(x, g0, g1, g2, g3, g4, g5, out, ks);
}